// Round 5
// baseline (434.034 us; speedup 1.0000x reference)
//
#include <hip/hip_runtime.h>
#include <hip/hip_bf16.h>

#define B_    8
#define NP    2352
#define D_    512
#define SENT  48
#define PAIRS 512
#define NERL  16
#define REL   32
#define MTOT  (B_*NP)   // 18816

typedef unsigned short u16;
typedef __bf16 bf16x8 __attribute__((ext_vector_type(8)));
typedef float  f32x4  __attribute__((ext_vector_type(4)));
typedef float  f32x16 __attribute__((ext_vector_type(16)));

__device__ __forceinline__ u16 f2b(float f) {
  union { float f; unsigned u; } c; c.f = f;
  unsigned u = c.u;
  u += 0x7fffu + ((u >> 16) & 1u);           // round-to-nearest-even
  return (u16)(u >> 16);
}
__device__ __forceinline__ float b2f(u16 h) {
  union { unsigned u; float f; } c; c.u = ((unsigned)h) << 16;
  return c.f;
}
__device__ __forceinline__ void gload16(const u16* g, u16* lds) {
  __builtin_amdgcn_global_load_lds(
      (const __attribute__((address_space(1))) unsigned*)g,
      (__attribute__((address_space(3))) unsigned*)lds, 16, 0, 0);
}

// ----------------------------------------------------------------- zero ----
__global__ void zero_zp(u16* zp) { zp[threadIdx.x] = 0; }

// ------------------------------------------------------------- prep_adj ----
__global__ __launch_bounds__(256) void prep_adj(const float* __restrict__ adj,
                                                u16* __restrict__ adjb,
                                                float* __restrict__ rdenom) {
  const int row = blockIdx.x;                 // 0..18815
  const float4* src = (const float4*)(adj + (size_t)row * NP);
  ushort4* dst = (ushort4*)(adjb + (size_t)row * NP);
  float s = 0.f;
  for (int i = threadIdx.x; i < NP / 4; i += 256) {
    float4 v = src[i];
    s += (v.x + v.y) + (v.z + v.w);
    ushort4 o; o.x = f2b(v.x); o.y = f2b(v.y); o.z = f2b(v.z); o.w = f2b(v.w);
    dst[i] = o;
  }
  #pragma unroll
  for (int o = 32; o > 0; o >>= 1) s += __shfl_down(s, o, 64);
  __shared__ float red[4];
  int w = threadIdx.x >> 6, l = threadIdx.x & 63;
  if (l == 0) red[w] = s;
  __syncthreads();
  if (threadIdx.x == 0)
    rdenom[row] = 1.f / (red[0] + red[1] + red[2] + red[3] + 1.f);
}

// ----------------------------------------------------- transpose-convert ---
__global__ __launch_bounds__(256) void tcvt(const float* __restrict__ in_,
                                            u16* __restrict__ out,
                                            int R, int C, size_t inb, size_t outb) {
  __shared__ u16 tile[64][65];
  const int b  = blockIdx.z;
  const int r0 = blockIdx.x * 64, c0 = blockIdx.y * 64;
  const int t  = threadIdx.x;
  const int tr = t >> 4, tc = (t & 15) * 4;
  #pragma unroll
  for (int i = 0; i < 4; ++i) {
    int rl = i * 16 + tr;
    int r  = r0 + rl;
    if (r < R) {
      const float* in = in_ + (size_t)b * inb + (size_t)r * C + c0 + tc;
      float4 v = *(const float4*)in;
      tile[rl][tc + 0] = f2b(v.x); tile[rl][tc + 1] = f2b(v.y);
      tile[rl][tc + 2] = f2b(v.z); tile[rl][tc + 3] = f2b(v.w);
    }
  }
  __syncthreads();
  const int c  = t >> 2;
  const int rb = (t & 3) * 16;
  u16* orow = out + (size_t)b * outb + (size_t)(c0 + c) * R + r0;
  #pragma unroll
  for (int i = 0; i < 4; ++i) {
    int rl = rb + i * 4;
    int r  = r0 + rl;
    if (r + 3 < R) {
      ushort4 v;
      v.x = tile[rl + 0][c]; v.y = tile[rl + 1][c];
      v.z = tile[rl + 2][c]; v.w = tile[rl + 3][c];
      *(ushort4*)(orow + rl) = v;
    } else {
      for (int j = 0; j < 4; ++j)
        if (r + j < R) orow[rl + j] = tile[rl + j][c];
    }
  }
}

// -------------------------------------------------- 8-wave 192x256 GEMM ----
// C[m][n] = sum_k A[m][k]*B[n][k] (both k-major). BM=192, BN=256, BK=32,
// 512 thr, 8 waves (2m x 4n), per-wave 96x64 = 3x2 frags of 32x32x16 bf16.
// 4-deep LDS ring (112 KB); per K-tile 2 phases (k-slice 0 / k-slice 1):
//   ph: 5 ds_read_b128, issue STAGE_{A|B}(t+3), barrier, lgkm(0),
//       setprio(1), 6 MFMA 32x32x16, setprio(0) [ph2: vmcnt(8)], barrier
// LDS chunk swizzle: slot = chunk ^ ((row>>1)&3) on BOTH sides -> 0 conflicts.
// K-tail / lookahead overrun redirect to a zero page.
// MODE 0: S=adj@X^T (+x epi, per-batch)  MODE 1: (S@W+2b)*rdenom,relu
// MODE 2: concat(g0,g1)@outw + b.  WRITE_T: also emit transposed bf16 out.
template<int MODE, int WRITE_T>
__global__ __launch_bounds__(512, 2) void gemm8(
    const u16* __restrict__ A, const u16* __restrict__ A2,
    const u16* __restrict__ Bm, const u16* __restrict__ Xt,
    const float* __restrict__ bias, const float* __restrict__ rdenom,
    const u16* __restrict__ zp, u16* __restrict__ out, u16* __restrict__ outT)
{
  constexpr int KACT   = (MODE == 0) ? NP : (MODE == 1 ? 512 : 1024);
  constexpr int KTILES = (KACT + 31) / 32;     // 74 / 16 / 32
  constexpr int LDA    = (MODE == 0) ? NP : 512;
  constexpr int LDB    = KACT;

  int m0, n0;
  const u16* Ab = A;
  const u16* Bb = Bm;
  const u16* Xb = Xt;
  size_t outBase = 0;
  if constexpr (MODE == 0) {
    // grid 208 = 8 XCDs x 26 (one batch per XCD); 13 m-tiles x 2 n-tiles
    const int bx  = blockIdx.x;
    const int bat = bx & 7;
    const int loc = bx >> 3;                  // 0..25
    const int mt  = loc >> 1;
    n0 = (loc & 1) << 8;
    m0 = (mt < 12) ? mt * 192 : NP - 192;     // overlap last tile
    Ab = A  + (size_t)bat * NP * NP;
    Bb = Bm + (size_t)bat * 512 * NP;
    Xb = Xt + (size_t)bat * 512 * NP;
    outBase = (size_t)bat * NP * 512;
  } else {
    // grid 196 = 98 m-tiles x 2; bijective XCD chunking (q=24, r=4)
    const int bx  = blockIdx.x;
    const int xcd = bx & 7, pos = bx >> 3;
    const int rid = (xcd < 4) ? xcd * 25 + pos : 100 + (xcd - 4) * 24 + pos;
    const int mt  = rid >> 1;
    n0 = (rid & 1) << 8;
    m0 = mt * 192;                            // exact (98*192 = 18816)
  }

  __shared__ __align__(16) u16 As[4 * 6144];   // 4 bufs x 192 rows x 32 k
  __shared__ __align__(16) u16 Bs[4 * 8192];   // 4 bufs x 256 rows x 32 k

  const int tid = threadIdx.x;
  const int l  = tid & 63;
  const int w  = tid >> 6;
  const int wm = w >> 2, wn = w & 3;
  const int lr = l & 31;      // frag row/col
  const int lh = l >> 5;      // k-half within slice

  f32x16 acc[3][2];
  #pragma unroll
  for (int i = 0; i < 3; ++i)
    #pragma unroll
    for (int j = 0; j < 2; ++j)
      acc[i][j] = (f32x16)(0.f);

  auto STAGE_A = [&](int buf, int kt) {       // 768 chunks; 2 issues/thread
    #pragma unroll
    for (int j = 0; j < 2; ++j) {
      const int cl  = (j == 0) ? tid : 512 + (tid & 255);  // dup keeps vmcnt uniform
      const int row = cl >> 2, c = cl & 3;
      const int gch = kt * 4 + (c ^ ((row >> 1) & 3));
      const int gm  = m0 + row;
      const u16* src;
      if constexpr (MODE == 2) {
        src = (gch < 64) ? A  + (size_t)gm * 512 + gch * 8
                         : A2 + (size_t)gm * 512 + (gch - 64) * 8;
      } else {
        src = Ab + (size_t)gm * LDA + gch * 8;
      }
      if (gch * 8 + 8 > KACT) src = zp;
      gload16(src, As + buf * 6144 + cl * 8);
    }
  };
  auto STAGE_B = [&](int buf, int kt) {       // 1024 chunks; 2 issues/thread
    #pragma unroll
    for (int j = 0; j < 2; ++j) {
      const int cl  = j * 512 + tid;
      const int row = cl >> 2, c = cl & 3;
      const int gch = kt * 4 + (c ^ ((row >> 1) & 3));
      const int gn  = n0 + row;
      const u16* src = Bb + (size_t)gn * LDB + gch * 8;
      if (gch * 8 + 8 > KACT) src = zp;
      gload16(src, Bs + buf * 8192 + cl * 8);
    }
  };

  // prologue: tiles 0,1,2 staged (12 issues/thread in flight)
  STAGE_A(0, 0); STAGE_B(0, 0);
  STAGE_A(1, 1); STAGE_B(1, 1);
  STAGE_A(2, 2); STAGE_B(2, 2);
  asm volatile("s_waitcnt vmcnt(8)" ::: "memory");   // tile 0 landed
  __builtin_amdgcn_s_barrier();

  for (int kt = 0; kt < KTILES; ++kt) {
    const int buf = kt & 3;
    const u16* Ac = As + buf * 6144;
    const u16* Bc = Bs + buf * 8192;
    bf16x8 af[3], bg[2];
    // ---------------- phase 1: k-slice 0, stage A(kt+3) ------------------
    #pragma unroll
    for (int f = 0; f < 3; ++f) {
      const int ra = wm * 96 + f * 32 + lr;
      af[f] = *(const bf16x8*)(Ac + ra * 32 + (((0 + lh) ^ ((ra >> 1) & 3)) << 3));
    }
    #pragma unroll
    for (int f = 0; f < 2; ++f) {
      const int rb = wn * 64 + f * 32 + lr;
      bg[f] = *(const bf16x8*)(Bc + rb * 32 + (((0 + lh) ^ ((rb >> 1) & 3)) << 3));
    }
    STAGE_A((kt + 3) & 3, kt + 3);
    __builtin_amdgcn_s_barrier();
    asm volatile("s_waitcnt lgkmcnt(0)" ::: "memory");
    __builtin_amdgcn_s_setprio(1);
    #pragma unroll
    for (int mi = 0; mi < 3; ++mi)
      #pragma unroll
      for (int ni = 0; ni < 2; ++ni)
        acc[mi][ni] = __builtin_amdgcn_mfma_f32_32x32x16_bf16(
            af[mi], bg[ni], acc[mi][ni], 0, 0, 0);
    __builtin_amdgcn_s_setprio(0);
    __builtin_amdgcn_s_barrier();
    // ---------------- phase 2: k-slice 1, stage B(kt+3) ------------------
    #pragma unroll
    for (int f = 0; f < 3; ++f) {
      const int ra = wm * 96 + f * 32 + lr;
      af[f] = *(const bf16x8*)(Ac + ra * 32 + (((2 + lh) ^ ((ra >> 1) & 3)) << 3));
    }
    #pragma unroll
    for (int f = 0; f < 2; ++f) {
      const int rb = wn * 64 + f * 32 + lr;
      bg[f] = *(const bf16x8*)(Bc + rb * 32 + (((2 + lh) ^ ((rb >> 1) & 3)) << 3));
    }
    STAGE_B((kt + 3) & 3, kt + 3);
    __builtin_amdgcn_s_barrier();
    asm volatile("s_waitcnt lgkmcnt(0)" ::: "memory");
    __builtin_amdgcn_s_setprio(1);
    #pragma unroll
    for (int mi = 0; mi < 3; ++mi)
      #pragma unroll
      for (int ni = 0; ni < 2; ++ni)
        acc[mi][ni] = __builtin_amdgcn_mfma_f32_32x32x16_bf16(
            af[mi], bg[ni], acc[mi][ni], 0, 0, 0);
    __builtin_amdgcn_s_setprio(0);
    asm volatile("s_waitcnt vmcnt(8)" ::: "memory");  // tile kt+1 landed
    __builtin_amdgcn_s_barrier();
  }

  // --------------------------------------------------------- epilogue ----
  // 32x32 C/D: col = l&31, row = (reg&3) + 8*(reg>>2) + 4*(l>>5)
  #pragma unroll
  for (int mi = 0; mi < 3; ++mi) {
    #pragma unroll
    for (int ni = 0; ni < 2; ++ni) {
      const int gn = n0 + wn * 64 + ni * 32 + lr;
      #pragma unroll
      for (int p = 0; p < 4; ++p) {
        const int gmq = m0 + wm * 96 + mi * 32 + 4 * lh + 8 * p;  // quad base
        u16 ov[4];
        if constexpr (MODE == 0) {
          ushort4 xv = *(const ushort4*)(Xb + (size_t)gn * NP + gmq);
          const float xf[4] = {b2f(xv.x), b2f(xv.y), b2f(xv.z), b2f(xv.w)};
          #pragma unroll
          for (int q = 0; q < 4; ++q)
            ov[q] = f2b(acc[mi][ni][4 * p + q] + xf[q]);
        } else if constexpr (MODE == 1) {
          const f32x4 rd = *(const f32x4*)(rdenom + gmq);
          const float bn = 2.f * bias[gn];
          #pragma unroll
          for (int q = 0; q < 4; ++q)
            ov[q] = f2b(fmaxf((acc[mi][ni][4 * p + q] + bn) * rd[q], 0.f));
        } else {
          const float bn = bias[gn];
          #pragma unroll
          for (int q = 0; q < 4; ++q)
            ov[q] = f2b(acc[mi][ni][4 * p + q] + bn);
        }
        #pragma unroll
        for (int q = 0; q < 4; ++q)
          out[outBase + (size_t)(gmq + q) * 512 + gn] = ov[q];
        if constexpr (WRITE_T) {
          const int bb = gmq / NP;
          const int ml = gmq - bb * NP;
          ushort4 tv; tv.x = ov[0]; tv.y = ov[1]; tv.z = ov[2]; tv.w = ov[3];
          *(ushort4*)(outT + ((size_t)bb * 512 + gn) * NP + ml) = tv;
        }
      }
    }
  }
}

// ------------------------------------------------------------- ner head ----
__global__ __launch_bounds__(64) void ner_kernel(const float* __restrict__ ner,
                                                 const u16* __restrict__ logits,
                                                 const float* __restrict__ nw,
                                                 const float* __restrict__ nb,
                                                 float* __restrict__ out) {
  int r = blockIdx.x;                 // 0..383
  int b = r / SENT, tp = r % SENT;
  int lane = threadIdx.x;
  const float* nrow = ner    + ((size_t)b * SENT + tp) * D_;
  const u16*   lrow = logits + ((size_t)b * NP   + tp) * D_;
  float rv[16];
  #pragma unroll
  for (int i = 0; i < 8; ++i) rv[i]     = nrow[lane + i * 64];
  #pragma unroll
  for (int i = 0; i < 8; ++i) rv[8 + i] = b2f(lrow[lane + i * 64]);
  for (int j = 0; j < NERL; ++j) {
    float s = 0.f;
    #pragma unroll
    for (int i = 0; i < 16; ++i)
      s = fmaf(rv[i], nw[(size_t)(lane + i * 64) * NERL + j], s);
    for (int o = 32; o > 0; o >>= 1) s += __shfl_down(s, o);
    if (lane == 0) out[r * NERL + j] = s + nb[j];
  }
}

// ----------------------------------------------------------- pair + re -----
__global__ __launch_bounds__(256) void pair_kernel(const u16* __restrict__ logits,
                                                   const float* __restrict__ refeat,
                                                   const float* __restrict__ rw,
                                                   const float* __restrict__ rb,
                                                   const int* __restrict__ ps,
                                                   const int* __restrict__ hs,
                                                   const int* __restrict__ ts,
                                                   float* __restrict__ out) {
  int p = blockIdx.x;
  __shared__ float avg[D_];
  int b = ps[p], h = hs[p], tt = ts[p];
  const u16* base = logits + (size_t)b * NP * D_;
  const u16* r00 = base + (size_t)((h + 1) * SENT + tt) * D_;
  const u16* r01 = base + (size_t)((h + 1) * SENT + tt + 1) * D_;
  const u16* r10 = base + (size_t)((h + 2) * SENT + tt) * D_;
  const u16* r11 = base + (size_t)((h + 2) * SENT + tt + 1) * D_;
  for (int d = threadIdx.x; d < D_; d += 256)
    avg[d] = 0.25f * (b2f(r00[d]) + b2f(r01[d]) + b2f(r10[d]) + b2f(r11[d]));
  __syncthreads();
  int wave = threadIdx.x >> 6, lane = threadIdx.x & 63;
  const float* rf = refeat + (size_t)p * D_;
  for (int jj = 0; jj < 8; ++jj) {
    int j = wave * 8 + jj;
    float s = 0.f;
    #pragma unroll
    for (int i = 0; i < 8; ++i) {
      int k = lane + i * 64;
      s = fmaf(rf[k],  rw[(size_t)k * REL + j], s);
      s = fmaf(avg[k], rw[(size_t)(k + D_) * REL + j], s);
    }
    for (int o = 32; o > 0; o >>= 1) s += __shfl_down(s, o);
    if (lane == 0) out[p * REL + j] = s + rb[j];
  }
}

// --------------------------------------------------------------- launch ----
extern "C" void kernel_launch(void* const* d_in, const int* in_sizes, int n_in,
                              void* d_out, int out_size, void* d_ws, size_t ws_size,
                              hipStream_t stream) {
  const float* inputs = (const float*)d_in[0];
  const float* ner    = (const float*)d_in[1];
  const float* refeat = (const float*)d_in[2];
  const float* adj    = (const float*)d_in[3];
  const float* W0w    = (const float*)d_in[4];
  const float* W0b    = (const float*)d_in[5];
  const float* W1w    = (const float*)d_in[6];
  const float* W1b    = (const float*)d_in[7];
  const float* outw   = (const float*)d_in[8];
  const float* outb   = (const float*)d_in[9];
  const float* nerw   = (const float*)d_in[10];
  const float* nerb   = (const float*)d_in[11];
  const float* rew    = (const float*)d_in[12];
  const float* reb    = (const float*)d_in[13];
  const int*   ps     = (const int*)d_in[14];
  const int*   hs     = (const int*)d_in[15];
  const int*   ts     = (const int*)d_in[16];
  (void)in_sizes; (void)n_in; (void)out_size; (void)ws_size;
  float* outp = (float*)d_out;

  char* ws = (char*)d_ws;
  size_t off = 0;
  u16* adj_bf = (u16*)(ws + off);               // 88,510,464 B
  u16* logits_bf = adj_bf;                      // overlay (adj dead by then)
  off += (size_t)B_ * NP * NP * 2;
  float* rdenom = (float*)(ws + off); off += (size_t)MTOT * 4;
  u16* zp  = (u16*)(ws + off); off += 512;
  u16* w0t = (u16*)(ws + off); off += 512 * 512 * 2;
  u16* w1t = (u16*)(ws + off); off += 512 * 512 * 2;
  u16* owt = (u16*)(ws + off); off += 512 * 1024 * 2;
  u16* xt  = (u16*)(ws + off); off += (size_t)B_ * 512 * NP * 2;  // x0t / g0t
  u16* S   = (u16*)(ws + off); off += (size_t)MTOT * 512 * 2;
  u16* g0  = (u16*)(ws + off); off += (size_t)MTOT * 512 * 2;
  u16* g1  = (u16*)(ws + off); off += (size_t)MTOT * 512 * 2;

  zero_zp<<<1, 256, 0, stream>>>(zp);
  prep_adj<<<MTOT, 256, 0, stream>>>(adj, adj_bf, rdenom);

  dim3 gT((NP + 63) / 64, D_ / 64, B_);         // (37, 8, 8)
  tcvt<<<gT, 256, 0, stream>>>(inputs, xt, NP, D_, (size_t)NP * D_, (size_t)D_ * NP);
  tcvt<<<dim3(8, 8, 1),  256, 0, stream>>>(W0w,  w0t, 512,  512, 0, 0);
  tcvt<<<dim3(8, 8, 1),  256, 0, stream>>>(W1w,  w1t, 512,  512, 0, 0);
  tcvt<<<dim3(16, 8, 1), 256, 0, stream>>>(outw, owt, 1024, 512, 0, 0);

  gemm8<0,0><<<208, 512, 0, stream>>>(adj_bf, nullptr, xt, xt,
                                      nullptr, nullptr, zp, S, nullptr);
  gemm8<1,1><<<196, 512, 0, stream>>>(S, nullptr, w0t, nullptr,
                                      W0b, rdenom, zp, g0, xt);
  gemm8<0,0><<<208, 512, 0, stream>>>(adj_bf, nullptr, xt, xt,
                                      nullptr, nullptr, zp, S, nullptr);
  gemm8<1,0><<<196, 512, 0, stream>>>(S, nullptr, w1t, nullptr,
                                      W1b, rdenom, zp, g1, nullptr);
  gemm8<2,0><<<196, 512, 0, stream>>>(g0, g1, owt, nullptr,
                                      outb, nullptr, zp, logits_bf, nullptr);

  ner_kernel <<<B_ * SENT, 64,  0, stream>>>(ner, logits_bf, nerw, nerb, outp);
  pair_kernel<<<PAIRS,     256, 0, stream>>>(logits_bf, refeat, rew, reb, ps, hs, ts,
                                             outp + B_ * SENT * NERL);
}

// Round 6
// 411.260 us; speedup vs baseline: 1.0554x; 1.0554x over previous
//
#include <hip/hip_runtime.h>
#include <hip/hip_bf16.h>

#define B_    8
#define NP    2352
#define D_    512
#define SENT  48
#define PAIRS 512
#define NERL  16
#define REL   32
#define MTOT  (B_*NP)   // 18816

typedef unsigned short u16;
typedef __bf16 bf16x8 __attribute__((ext_vector_type(8)));
typedef float  f32x4  __attribute__((ext_vector_type(4)));

__device__ __forceinline__ u16 f2b(float f) {
  union { float f; unsigned u; } c; c.f = f;
  unsigned u = c.u;
  u += 0x7fffu + ((u >> 16) & 1u);           // round-to-nearest-even
  return (u16)(u >> 16);
}
__device__ __forceinline__ float b2f(u16 h) {
  union { unsigned u; float f; } c; c.u = ((unsigned)h) << 16;
  return c.f;
}
__device__ __forceinline__ void gload16(const u16* g, u16* lds) {
  __builtin_amdgcn_global_load_lds(
      (const __attribute__((address_space(1))) unsigned*)g,
      (__attribute__((address_space(3))) unsigned*)lds, 16, 0, 0);
}

// ----------------------------------------------------------------- zero ----
__global__ void zero_zp(u16* zp) { zp[threadIdx.x] = 0; }

// ------------------------------------------------------------- prep_adj ----
__global__ __launch_bounds__(256) void prep_adj(const float* __restrict__ adj,
                                                u16* __restrict__ adjb,
                                                float* __restrict__ rdenom) {
  const int row = blockIdx.x;                 // 0..18815
  const float4* src = (const float4*)(adj + (size_t)row * NP);
  ushort4* dst = (ushort4*)(adjb + (size_t)row * NP);
  float s = 0.f;
  for (int i = threadIdx.x; i < NP / 4; i += 256) {
    float4 v = src[i];
    s += (v.x + v.y) + (v.z + v.w);
    ushort4 o; o.x = f2b(v.x); o.y = f2b(v.y); o.z = f2b(v.z); o.w = f2b(v.w);
    dst[i] = o;
  }
  #pragma unroll
  for (int o = 32; o > 0; o >>= 1) s += __shfl_down(s, o, 64);
  __shared__ float red[4];
  int w = threadIdx.x >> 6, l = threadIdx.x & 63;
  if (l == 0) red[w] = s;
  __syncthreads();
  if (threadIdx.x == 0)
    rdenom[row] = 1.f / (red[0] + red[1] + red[2] + red[3] + 1.f);
}

// ----------------------------------------------------- transpose-convert ---
__global__ __launch_bounds__(256) void tcvt(const float* __restrict__ in_,
                                            u16* __restrict__ out,
                                            int R, int C, size_t inb, size_t outb) {
  __shared__ u16 tile[64][65];
  const int b  = blockIdx.z;
  const int r0 = blockIdx.x * 64, c0 = blockIdx.y * 64;
  const int t  = threadIdx.x;
  const int tr = t >> 4, tc = (t & 15) * 4;
  #pragma unroll
  for (int i = 0; i < 4; ++i) {
    int rl = i * 16 + tr;
    int r  = r0 + rl;
    if (r < R) {
      const float* in = in_ + (size_t)b * inb + (size_t)r * C + c0 + tc;
      float4 v = *(const float4*)in;
      tile[rl][tc + 0] = f2b(v.x); tile[rl][tc + 1] = f2b(v.y);
      tile[rl][tc + 2] = f2b(v.z); tile[rl][tc + 3] = f2b(v.w);
    }
  }
  __syncthreads();
  const int c  = t >> 2;
  const int rb = (t & 3) * 16;
  u16* orow = out + (size_t)b * outb + (size_t)(c0 + c) * R + r0;
  #pragma unroll
  for (int i = 0; i < 4; ++i) {
    int rl = rb + i * 4;
    int r  = r0 + rl;
    if (r + 3 < R) {
      ushort4 v;
      v.x = tile[rl + 0][c]; v.y = tile[rl + 1][c];
      v.z = tile[rl + 2][c]; v.w = tile[rl + 3][c];
      *(ushort4*)(orow + rl) = v;
    } else {
      for (int j = 0; j < 4; ++j)
        if (r + j < R) orow[rl + j] = tile[rl + j][c];
    }
  }
}

// -------------------------------------------------- 8-wave 256x256 GEMM ----
// Same as R4 geometry (BM=BN=256, BK=32, 8 waves 2x4, per-wave 128x64,
// 16x16x32 MFMA, 4-deep LDS ring, counted vmcnt(8), chunk XOR swizzle),
// PLUS sched_barrier(0) pins so hipcc cannot hoist/sink the register-only
// MFMA clusters across the inline-asm waitcnt/barrier skeleton (rule #18).
template<int MODE, int WRITE_T>
__global__ __launch_bounds__(512, 2) void gemm8(
    const u16* __restrict__ A, const u16* __restrict__ A2,
    const u16* __restrict__ Bm, const u16* __restrict__ Xt,
    const float* __restrict__ bias, const float* __restrict__ rdenom,
    const u16* __restrict__ zp, u16* __restrict__ out, u16* __restrict__ outT)
{
  constexpr int KACT   = (MODE == 0) ? NP : (MODE == 1 ? 512 : 1024);
  constexpr int KTILES = (KACT + 31) / 32;     // 74 / 16 / 32
  constexpr int LDA    = (MODE == 0) ? NP : 512;
  constexpr int LDB    = KACT;

  int m0, n0;
  const u16* Ab = A;
  const u16* Bb = Bm;
  const u16* Xb = Xt;
  size_t outBase = 0;
  if constexpr (MODE == 0) {
    // grid 160 = 8 XCDs x 20 (one batch per XCD); 10 m-tiles x 2 n-tiles
    const int bx  = blockIdx.x;
    const int bat = bx & 7;
    const int loc = bx >> 3;                  // 0..19
    const int mt  = loc >> 1;
    n0 = (loc & 1) << 8;
    m0 = (mt < 9) ? mt * 256 : NP - 256;      // overlap last tile
    Ab = A  + (size_t)bat * NP * NP;
    Bb = Bm + (size_t)bat * 512 * NP;
    Xb = Xt + (size_t)bat * 512 * NP;
    outBase = (size_t)bat * NP * 512;
  } else {
    // grid 148; bijective XCD chunking (q=18, r=4)
    const int bx  = blockIdx.x;
    const int xcd = bx & 7, pos = bx >> 3;
    const int rid = (xcd < 4) ? xcd * 19 + pos : 76 + (xcd - 4) * 18 + pos;
    const int mt  = rid >> 1;
    n0 = (rid & 1) << 8;
    m0 = (mt < 73) ? mt * 256 : MTOT - 256;   // overlap last tile
  }

  __shared__ __align__(16) u16 As[4 * 8192];   // 4 bufs x 256 rows x 32 k
  __shared__ __align__(16) u16 Bs[4 * 8192];

  const int tid = threadIdx.x;
  const int l  = tid & 63;
  const int w  = tid >> 6;
  const int wm = w >> 2, wn = w & 3;
  const int lr = l & 15, lq = l >> 4;

  f32x4 acc[8][4];
  #pragma unroll
  for (int i = 0; i < 8; ++i)
    #pragma unroll
    for (int j = 0; j < 4; ++j)
      acc[i][j] = (f32x4){0.f, 0.f, 0.f, 0.f};

  auto STAGE_A = [&](int buf, int kt) {
    #pragma unroll
    for (int j = 0; j < 2; ++j) {
      const int cl  = j * 512 + tid;            // 0..1023
      const int row = cl >> 2, c = cl & 3;
      const int gch = kt * 4 + (c ^ ((row >> 1) & 3));  // logical 16B chunk
      const int gm  = m0 + row;                 // always in-range (overlap)
      const u16* src;
      if constexpr (MODE == 2) {
        src = (gch < 64) ? A  + (size_t)gm * 512 + gch * 8
                         : A2 + (size_t)gm * 512 + (gch - 64) * 8;
      } else {
        src = Ab + (size_t)gm * LDA + gch * 8;
      }
      if (gch * 8 + 8 > KACT) src = zp;         // k-tail / lookahead -> zeros
      gload16(src, As + buf * 8192 + cl * 8);
    }
  };
  auto STAGE_B = [&](int buf, int kt) {
    #pragma unroll
    for (int j = 0; j < 2; ++j) {
      const int cl  = j * 512 + tid;
      const int row = cl >> 2, c = cl & 3;
      const int gch = kt * 4 + (c ^ ((row >> 1) & 3));
      const int gn  = n0 + row;
      const u16* src = Bb + (size_t)gn * LDB + gch * 8;
      if (gch * 8 + 8 > KACT) src = zp;
      gload16(src, Bs + buf * 8192 + cl * 8);
    }
  };

  // prologue: tiles 0,1,2 staged (12 issues/thread in flight)
  STAGE_A(0, 0); STAGE_B(0, 0);
  STAGE_A(1, 1); STAGE_B(1, 1);
  STAGE_A(2, 2); STAGE_B(2, 2);
  asm volatile("s_waitcnt vmcnt(8)" ::: "memory");   // tile 0 landed
  __builtin_amdgcn_sched_barrier(0);
  __builtin_amdgcn_s_barrier();

  for (int kt = 0; kt < KTILES; ++kt) {
    const int buf = kt & 3;
    const u16* Ac = As + buf * 8192;
    const u16* Bc = Bs + buf * 8192;
    bf16x8 af[4], bg[4];
    // ---------------- phase 1: qm0 + all B, stage A(kt+3) ----------------
    #pragma unroll
    for (int f = 0; f < 4; ++f) {
      const int ra = wm * 128 + f * 16 + lr;
      af[f] = *(const bf16x8*)(Ac + ra * 32 + ((lq ^ ((ra >> 1) & 3)) << 3));
      const int rb = wn * 64 + f * 16 + lr;
      bg[f] = *(const bf16x8*)(Bc + rb * 32 + ((lq ^ ((rb >> 1) & 3)) << 3));
    }
    STAGE_A((kt + 3) & 3, kt + 3);
    __builtin_amdgcn_s_barrier();
    asm volatile("s_waitcnt lgkmcnt(0)" ::: "memory");
    __builtin_amdgcn_sched_barrier(0);          // pin: nothing crosses (r18)
    __builtin_amdgcn_s_setprio(1);
    #pragma unroll
    for (int mf = 0; mf < 4; ++mf)
      #pragma unroll
      for (int nf = 0; nf < 4; ++nf)
        acc[mf][nf] = __builtin_amdgcn_mfma_f32_16x16x32_bf16(
            af[mf], bg[nf], acc[mf][nf], 0, 0, 0);
    __builtin_amdgcn_s_setprio(0);
    __builtin_amdgcn_sched_barrier(0);          // pin MFMA cluster end
    __builtin_amdgcn_s_barrier();
    // ---------------- phase 2: qm1 (B reused), stage B(kt+3) -------------
    #pragma unroll
    for (int f = 0; f < 4; ++f) {
      const int ra = wm * 128 + 64 + f * 16 + lr;
      af[f] = *(const bf16x8*)(Ac + ra * 32 + ((lq ^ ((ra >> 1) & 3)) << 3));
    }
    STAGE_B((kt + 3) & 3, kt + 3);
    __builtin_amdgcn_s_barrier();
    asm volatile("s_waitcnt lgkmcnt(0)" ::: "memory");
    __builtin_amdgcn_sched_barrier(0);
    __builtin_amdgcn_s_setprio(1);
    #pragma unroll
    for (int mf = 0; mf < 4; ++mf)
      #pragma unroll
      for (int nf = 0; nf < 4; ++nf)
        acc[4 + mf][nf] = __builtin_amdgcn_mfma_f32_16x16x32_bf16(
            af[mf], bg[nf], acc[4 + mf][nf], 0, 0, 0);
    __builtin_amdgcn_s_setprio(0);
    __builtin_amdgcn_sched_barrier(0);
    asm volatile("s_waitcnt vmcnt(8)" ::: "memory");  // tile kt+1 landed
    __builtin_amdgcn_sched_barrier(0);
    __builtin_amdgcn_s_barrier();
  }

  // --------------------------------------------------------- epilogue ----
  #pragma unroll
  for (int mf = 0; mf < 8; ++mf) {
    const int gm0 = m0 + wm * 128 + mf * 16 + lq * 4;
    f32x4 rd;
    if constexpr (MODE == 1) rd = *(const f32x4*)(rdenom + gm0);
    #pragma unroll
    for (int nf = 0; nf < 4; ++nf) {
      const int gn = n0 + wn * 64 + nf * 16 + lr;
      u16 ov[4];
      if constexpr (MODE == 0) {
        ushort4 xv = *(const ushort4*)(Xb + (size_t)gn * NP + gm0);
        const float xf[4] = {b2f(xv.x), b2f(xv.y), b2f(xv.z), b2f(xv.w)};
        #pragma unroll
        for (int r = 0; r < 4; ++r) ov[r] = f2b(acc[mf][nf][r] + xf[r]);
      } else if constexpr (MODE == 1) {
        const float bn = 2.f * bias[gn];
        #pragma unroll
        for (int r = 0; r < 4; ++r)
          ov[r] = f2b(fmaxf((acc[mf][nf][r] + bn) * rd[r], 0.f));
      } else {
        const float bn = bias[gn];
        #pragma unroll
        for (int r = 0; r < 4; ++r) ov[r] = f2b(acc[mf][nf][r] + bn);
      }
      #pragma unroll
      for (int r = 0; r < 4; ++r)
        out[outBase + (size_t)(gm0 + r) * 512 + gn] = ov[r];
      if constexpr (WRITE_T) {
        const int bb = gm0 / NP;                 // batch of this row-quad
        const int ml = gm0 - bb * NP;
        ushort4 tv; tv.x = ov[0]; tv.y = ov[1]; tv.z = ov[2]; tv.w = ov[3];
        *(ushort4*)(outT + ((size_t)bb * 512 + gn) * NP + ml) = tv;
      }
    }
  }
}

// ------------------------------------------------------------- ner head ----
__global__ __launch_bounds__(64) void ner_kernel(const float* __restrict__ ner,
                                                 const u16* __restrict__ logits,
                                                 const float* __restrict__ nw,
                                                 const float* __restrict__ nb,
                                                 float* __restrict__ out) {
  int r = blockIdx.x;                 // 0..383
  int b = r / SENT, tp = r % SENT;
  int lane = threadIdx.x;
  const float* nrow = ner    + ((size_t)b * SENT + tp) * D_;
  const u16*   lrow = logits + ((size_t)b * NP   + tp) * D_;
  float rv[16];
  #pragma unroll
  for (int i = 0; i < 8; ++i) rv[i]     = nrow[lane + i * 64];
  #pragma unroll
  for (int i = 0; i < 8; ++i) rv[8 + i] = b2f(lrow[lane + i * 64]);
  for (int j = 0; j < NERL; ++j) {
    float s = 0.f;
    #pragma unroll
    for (int i = 0; i < 16; ++i)
      s = fmaf(rv[i], nw[(size_t)(lane + i * 64) * NERL + j], s);
    for (int o = 32; o > 0; o >>= 1) s += __shfl_down(s, o);
    if (lane == 0) out[r * NERL + j] = s + nb[j];
  }
}

// ----------------------------------------------------------- pair + re -----
__global__ __launch_bounds__(256) void pair_kernel(const u16* __restrict__ logits,
                                                   const float* __restrict__ refeat,
                                                   const float* __restrict__ rw,
                                                   const float* __restrict__ rb,
                                                   const int* __restrict__ ps,
                                                   const int* __restrict__ hs,
                                                   const int* __restrict__ ts,
                                                   float* __restrict__ out) {
  int p = blockIdx.x;
  __shared__ float avg[D_];
  int b = ps[p], h = hs[p], tt = ts[p];
  const u16* base = logits + (size_t)b * NP * D_;
  const u16* r00 = base + (size_t)((h + 1) * SENT + tt) * D_;
  const u16* r01 = base + (size_t)((h + 1) * SENT + tt + 1) * D_;
  const u16* r10 = base + (size_t)((h + 2) * SENT + tt) * D_;
  const u16* r11 = base + (size_t)((h + 2) * SENT + tt + 1) * D_;
  for (int d = threadIdx.x; d < D_; d += 256)
    avg[d] = 0.25f * (b2f(r00[d]) + b2f(r01[d]) + b2f(r10[d]) + b2f(r11[d]));
  __syncthreads();
  int wave = threadIdx.x >> 6, lane = threadIdx.x & 63;
  const float* rf = refeat + (size_t)p * D_;
  for (int jj = 0; jj < 8; ++jj) {
    int j = wave * 8 + jj;
    float s = 0.f;
    #pragma unroll
    for (int i = 0; i < 8; ++i) {
      int k = lane + i * 64;
      s = fmaf(rf[k],  rw[(size_t)k * REL + j], s);
      s = fmaf(avg[k], rw[(size_t)(k + D_) * REL + j], s);
    }
    for (int o = 32; o > 0; o >>= 1) s += __shfl_down(s, o);
    if (lane == 0) out[p * REL + j] = s + rb[j];
  }
}

// --------------------------------------------------------------- launch ----
extern "C" void kernel_launch(void* const* d_in, const int* in_sizes, int n_in,
                              void* d_out, int out_size, void* d_ws, size_t ws_size,
                              hipStream_t stream) {
  const float* inputs = (const float*)d_in[0];
  const float* ner    = (const float*)d_in[1];
  const float* refeat = (const float*)d_in[2];
  const float* adj    = (const float*)d_in[3];
  const float* W0w    = (const float*)d_in[4];
  const float* W0b    = (const float*)d_in[5];
  const float* W1w    = (const float*)d_in[6];
  const float* W1b    = (const float*)d_in[7];
  const float* outw   = (const float*)d_in[8];
  const float* outb   = (const float*)d_in[9];
  const float* nerw   = (const float*)d_in[10];
  const float* nerb   = (const float*)d_in[11];
  const float* rew    = (const float*)d_in[12];
  const float* reb    = (const float*)d_in[13];
  const int*   ps     = (const int*)d_in[14];
  const int*   hs     = (const int*)d_in[15];
  const int*   ts     = (const int*)d_in[16];
  (void)in_sizes; (void)n_in; (void)out_size; (void)ws_size;
  float* outp = (float*)d_out;

  char* ws = (char*)d_ws;
  size_t off = 0;
  u16* adj_bf = (u16*)(ws + off);               // 88,510,464 B
  u16* logits_bf = adj_bf;                      // overlay (adj dead by then)
  off += (size_t)B_ * NP * NP * 2;
  float* rdenom = (float*)(ws + off); off += (size_t)MTOT * 4;
  u16* zp  = (u16*)(ws + off); off += 512;
  u16* w0t = (u16*)(ws + off); off += 512 * 512 * 2;
  u16* w1t = (u16*)(ws + off); off += 512 * 512 * 2;
  u16* owt = (u16*)(ws + off); off += 512 * 1024 * 2;
  u16* xt  = (u16*)(ws + off); off += (size_t)B_ * 512 * NP * 2;  // x0t / g0t
  u16* S   = (u16*)(ws + off); off += (size_t)MTOT * 512 * 2;
  u16* g0  = (u16*)(ws + off); off += (size_t)MTOT * 512 * 2;
  u16* g1  = (u16*)(ws + off); off += (size_t)MTOT * 512 * 2;

  zero_zp<<<1, 256, 0, stream>>>(zp);
  prep_adj<<<MTOT, 256, 0, stream>>>(adj, adj_bf, rdenom);

  dim3 gT((NP + 63) / 64, D_ / 64, B_);         // (37, 8, 8)
  tcvt<<<gT, 256, 0, stream>>>(inputs, xt, NP, D_, (size_t)NP * D_, (size_t)D_ * NP);
  tcvt<<<dim3(8, 8, 1),  256, 0, stream>>>(W0w,  w0t, 512,  512, 0, 0);
  tcvt<<<dim3(8, 8, 1),  256, 0, stream>>>(W1w,  w1t, 512,  512, 0, 0);
  tcvt<<<dim3(16, 8, 1), 256, 0, stream>>>(outw, owt, 1024, 512, 0, 0);

  gemm8<0,0><<<160, 512, 0, stream>>>(adj_bf, nullptr, xt, xt,
                                      nullptr, nullptr, zp, S, nullptr);
  gemm8<1,1><<<148, 512, 0, stream>>>(S, nullptr, w0t, nullptr,
                                      W0b, rdenom, zp, g0, xt);
  gemm8<0,0><<<160, 512, 0, stream>>>(adj_bf, nullptr, xt, xt,
                                      nullptr, nullptr, zp, S, nullptr);
  gemm8<1,0><<<148, 512, 0, stream>>>(S, nullptr, w1t, nullptr,
                                      W1b, rdenom, zp, g1, nullptr);
  gemm8<2,0><<<148, 512, 0, stream>>>(g0, g1, owt, nullptr,
                                      outb, nullptr, zp, logits_bf, nullptr);

  ner_kernel <<<B_ * SENT, 64,  0, stream>>>(ner, logits_bf, nerw, nerb, outp);
  pair_kernel<<<PAIRS,     256, 0, stream>>>(logits_bf, refeat, rew, reb, ps, hs, ts,
                                             outp + B_ * SENT * NERL);
}